// Round 4
// baseline (121.313 us; speedup 1.0000x reference)
//
#include <hip/hip_runtime.h>

// Problem constants
#define B_  16
#define T_  256
#define K_  128
#define DK_ 256
#define U_  128
#define TT_ 4      // timesteps per attn block (grid = 16*64 = 1024 -> 4 blocks/CU)

#define SCALE_ 2.8853900817779268f  // 2*log2(e): exp(2x) = exp2(SCALE_*x)

// Km2 = exp2(SCALE_*(knw@W2+b2)) -- the only cross-kernel intermediate.
// (Cooperative single-kernel fusion fails under graph capture -> two
//  stream-ordered kernels.)
__device__ float g_Km2[B_ * K_ * U_];

// ---------------------------------------------------------------------------
// Km-only GEMM: 256 blocks x 256 threads (R3's 128 blocks used half the GPU
// and sits on the critical path before attn_ctx). Block = 8 rows; W2 read
// ~once per block (33 MB L2 total), d-split across threads + LDS reduce.
// ---------------------------------------------------------------------------
__global__ __launch_bounds__(256) void gemm_km(const float* __restrict__ knw,
                                               const float* __restrict__ W2,
                                               const float* __restrict__ b2) {
    __shared__ float Xs[8][256];        // 8 KB staged rows
    __shared__ float part[4][8][128];   // 16 KB dq-partials

    const int tid  = threadIdx.x;
    const int row0 = blockIdx.x * 8;    // flat row: b = row>>7, k = row&127

    // Stage 8 rows x 256 floats = 512 float4, 2 per thread, coalesced.
#pragma unroll
    for (int j = 0; j < 2; j++) {
        const int i  = tid + j * 256;
        const int rr = i >> 6, cc = i & 63;
        *(float4*)&Xs[rr][cc * 4] =
            *(const float4*)&knw[(row0 + rr) * 256 + cc * 4];
    }
    __syncthreads();

    // thread = (u4=4*(tid&31), dq=(tid>>5)&3, rh=tid>>7): 4 rows x 4 u x 64 d
    {
        const int uc = tid & 31;
        const int dq = (tid >> 5) & 3;
        const int rh = tid >> 7;
        float4 acc[4];
#pragma unroll
        for (int r = 0; r < 4; r++) acc[r] = make_float4(0.f, 0.f, 0.f, 0.f);
#pragma unroll 8
        for (int j = 0; j < 64; j++) {
            const int d = dq * 64 + j;
            const float4 w = *(const float4*)&W2[d * U_ + uc * 4];
#pragma unroll
            for (int r = 0; r < 4; r++) {
                const float x = Xs[rh * 4 + r][d];   // LDS broadcast
                acc[r].x = fmaf(x, w.x, acc[r].x);
                acc[r].y = fmaf(x, w.y, acc[r].y);
                acc[r].z = fmaf(x, w.z, acc[r].z);
                acc[r].w = fmaf(x, w.w, acc[r].w);
            }
        }
#pragma unroll
        for (int r = 0; r < 4; r++)
            *(float4*)&part[dq][rh * 4 + r][uc * 4] = acc[r];
    }
    __syncthreads();

    // Reduce 4 dq-partials: 1024 outputs / 256 threads = 4 each.
#pragma unroll
    for (int i = 0; i < 4; i++) {
        const int idx = tid + i * 256;
        const int r = idx >> 7, u = idx & 127;
        float s = b2[u];
#pragma unroll
        for (int dq = 0; dq < 4; dq++) s += part[dq][r][u];
        g_Km2[(row0 + r) * U_ + u] = __builtin_amdgcn_exp2f(SCALE_ * s);
    }
}

// ---------------------------------------------------------------------------
// Fused E-gemm -> scores -> softmax -> context. One block per (b, 4 t's).
// km (g_Km2) loads are issued at the TOP of the kernel: they were previously
// issued after the A1 barrier and consumed ~25 slots later -> full L2-miss
// latency exposed (g_Km2 freshly written on other XCDs), with all 4
// waves/SIMD stalling together. Issued here, A0 staging + A1's ~1340 cycles
// of fma cover the round trip.
// ---------------------------------------------------------------------------
__global__ __launch_bounds__(256, 4) void attn_ctx(const float* __restrict__ knw,
                                                   const float* __restrict__ enc,
                                                   const float* __restrict__ W1,
                                                   const float* __restrict__ b1,
                                                   const float* __restrict__ V,
                                                   float* __restrict__ out) {
    __shared__ float sm[4][TT_][256];   // 16 KB: E-partials / pA / ctx parts
    __shared__ float encs[TT_][256];    // 4 KB staged enc rows
    __shared__ float E2s[TT_][U_];      // 2 KB exp2 of own E rows
    __shared__ float attn[TT_][K_];     // 2 KB
    __shared__ float V2s[U_];           // 0.5 KB  2*V
    float* const smf = &sm[0][0][0];    // 4096 floats, multi-use

    const int tid  = threadIdx.x;
    const int blk  = blockIdx.x;
    const int b    = blk >> 6;          // 64 t-tiles per batch
    const int t0   = (blk & 63) * TT_;
    const int lane = tid & 63;
    const int wave = tid >> 6;

    // ---- km prefetch: 16 independent global float4, issued first ----
    const int k_idx = tid & 127;
    const int half  = tid >> 7;
    float4 km[16];
    {
        const float* kp = &g_Km2[(b * K_ + k_idx) * U_ + half * 64];
#pragma unroll
        for (int c = 0; c < 16; c++) km[c] = *(const float4*)&kp[c * 4];
    }

    // ---- A0: stage enc (4 rows x 256) + V ----
    {
        const int rr = tid >> 6, cc = tid & 63;
        *(float4*)&encs[rr][cc * 4] =
            *(const float4*)&enc[(b * T_ + t0 + rr) * 256 + cc * 4];
        if (tid < 128) V2s[tid] = 2.0f * V[tid];
    }
    __syncthreads();

    // ---- A1: E partial dots. thread = (u4=4*(tid&31), dq=tid>>5). ----
    // W1 read once per block, coalesced float4.
    {
        const int uc = tid & 31;
        const int dq = tid >> 5;        // d in [dq*32, dq*32+32)
        float4 a0 = {0,0,0,0}, a1 = {0,0,0,0}, a2 = {0,0,0,0}, a3 = {0,0,0,0};
#pragma unroll 8
        for (int j = 0; j < 32; j++) {
            const int d = dq * 32 + j;
            const float4 w = *(const float4*)&W1[d * U_ + uc * 4];
            const float e0 = encs[0][d], e1 = encs[1][d];
            const float e2 = encs[2][d], e3 = encs[3][d];
            a0.x = fmaf(e0, w.x, a0.x); a0.y = fmaf(e0, w.y, a0.y);
            a0.z = fmaf(e0, w.z, a0.z); a0.w = fmaf(e0, w.w, a0.w);
            a1.x = fmaf(e1, w.x, a1.x); a1.y = fmaf(e1, w.y, a1.y);
            a1.z = fmaf(e1, w.z, a1.z); a1.w = fmaf(e1, w.w, a1.w);
            a2.x = fmaf(e2, w.x, a2.x); a2.y = fmaf(e2, w.y, a2.y);
            a2.z = fmaf(e2, w.z, a2.z); a2.w = fmaf(e2, w.w, a2.w);
            a3.x = fmaf(e3, w.x, a3.x); a3.y = fmaf(e3, w.y, a3.y);
            a3.z = fmaf(e3, w.z, a3.z); a3.w = fmaf(e3, w.w, a3.w);
        }
        *(float4*)&smf[(dq * 4 + 0) * 128 + uc * 4] = a0;
        *(float4*)&smf[(dq * 4 + 1) * 128 + uc * 4] = a1;
        *(float4*)&smf[(dq * 4 + 2) * 128 + uc * 4] = a2;
        *(float4*)&smf[(dq * 4 + 3) * 128 + uc * 4] = a3;
    }
    __syncthreads();

    // ---- A2: reduce 8 dq-partials + bias + exp2 -> E2s ----
    {
        const int ti = tid >> 6, uu = tid & 63;
#pragma unroll
        for (int h = 0; h < 128; h += 64) {
            float s = b1[uu + h];
#pragma unroll
            for (int dq = 0; dq < 8; dq++)
                s += smf[(dq * 4 + ti) * 128 + uu + h];
            E2s[ti][uu + h] = __builtin_amdgcn_exp2f(SCALE_ * s);
        }
    }
    __syncthreads();

    float* const pA = smf;              // [TT_][256] score partials

    // ---- Phase 1: na[t] = sum_{u in half} 2V[u] * rcp(1 + ee*ek) ----
    // E2s/V2s reads are wave-uniform -> LDS broadcast. inf/0 products
    // saturate to the exact sigmoid limits (rcp(inf)=0, r=1).
    {
        float na[TT_] = {0.f, 0.f, 0.f, 0.f};
#pragma unroll
        for (int c = 0; c < 16; c++) {
            const float4 v4 = *(const float4*)&V2s[half * 64 + c * 4];
#pragma unroll
            for (int t = 0; t < TT_; t++) {
                const float4 e4 = *(const float4*)&E2s[t][half * 64 + c * 4];
                float r;
                r = __builtin_amdgcn_rcpf(fmaf(e4.x, km[c].x, 1.0f));
                na[t] = fmaf(v4.x, r, na[t]);
                r = __builtin_amdgcn_rcpf(fmaf(e4.y, km[c].y, 1.0f));
                na[t] = fmaf(v4.y, r, na[t]);
                r = __builtin_amdgcn_rcpf(fmaf(e4.z, km[c].z, 1.0f));
                na[t] = fmaf(v4.z, r, na[t]);
                r = __builtin_amdgcn_rcpf(fmaf(e4.w, km[c].w, 1.0f));
                na[t] = fmaf(v4.w, r, na[t]);
            }
        }
#pragma unroll
        for (int t = 0; t < TT_; t++) pA[t * 256 + tid] = na[t];
    }
    __syncthreads();

    // ---- Softmax over K=128: wave w owns timestep w ----
    {
        const int t = wave;
        const float* p = &pA[t * 256];
        float s0 = -(p[lane] + p[128 + lane]);
        float s1 = -(p[64 + lane] + p[192 + lane]);
        float m = fmaxf(s0, s1);
#pragma unroll
        for (int off = 32; off >= 1; off >>= 1)
            m = fmaxf(m, __shfl_xor(m, off));
        const float e0 = __builtin_amdgcn_exp2f(1.4426950408889634f * (s0 - m));
        const float e1 = __builtin_amdgcn_exp2f(1.4426950408889634f * (s1 - m));
        float ss = e0 + e1;
#pragma unroll
        for (int off = 32; off >= 1; off >>= 1)
            ss += __shfl_xor(ss, off);
        const float rinv = __builtin_amdgcn_rcpf(ss);
        attn[t][lane]      = e0 * rinv;
        attn[t][64 + lane] = e1 * rinv;
    }
    __syncthreads();

    // ---- Phase 2: context[ti][d] = sum_k attn[ti][k]*knw[b][k][d] ----
    // Wave kg covers k in [32kg, 32kg+32); lane covers d4 = 4*lane.
    {
        const int kg = wave, dq = lane;
        float4 acc[TT_];
#pragma unroll
        for (int ti = 0; ti < TT_; ti++) acc[ti] = make_float4(0.f, 0.f, 0.f, 0.f);

        const float* kp = &knw[(b * K_ + kg * 32) * DK_ + dq * 4];
#pragma unroll 4
        for (int ki = 0; ki < 32; ki++) {
            const float4 kn = *(const float4*)&kp[ki * DK_];
#pragma unroll
            for (int ti = 0; ti < TT_; ti++) {
                const float a = attn[ti][kg * 32 + ki];   // LDS broadcast
                acc[ti].x = fmaf(a, kn.x, acc[ti].x);
                acc[ti].y = fmaf(a, kn.y, acc[ti].y);
                acc[ti].z = fmaf(a, kn.z, acc[ti].z);
                acc[ti].w = fmaf(a, kn.w, acc[ti].w);
            }
        }
#pragma unroll
        for (int ti = 0; ti < TT_; ti++)
            *(float4*)&smf[(kg * TT_ + ti) * 256 + dq * 4] = acc[ti];
    }
    __syncthreads();

    // Cross-wave K reduction + coalesced float4 store (4 rows x 256)
    {
        const int ti = tid >> 6, dd = tid & 63;
        const float4 s0 = *(const float4*)&smf[(0 * TT_ + ti) * 256 + dd * 4];
        const float4 s1 = *(const float4*)&smf[(1 * TT_ + ti) * 256 + dd * 4];
        const float4 s2 = *(const float4*)&smf[(2 * TT_ + ti) * 256 + dd * 4];
        const float4 s3 = *(const float4*)&smf[(3 * TT_ + ti) * 256 + dd * 4];
        float4 o;
        o.x = s0.x + s1.x + s2.x + s3.x;
        o.y = s0.y + s1.y + s2.y + s3.y;
        o.z = s0.z + s1.z + s2.z + s3.z;
        o.w = s0.w + s1.w + s2.w + s3.w;
        *(float4*)&out[(b * T_ + t0 + ti) * DK_ + dd * 4] = o;
    }
}

// ---------------------------------------------------------------------------
extern "C" void kernel_launch(void* const* d_in, const int* in_sizes, int n_in,
                              void* d_out, int out_size, void* d_ws,
                              size_t ws_size, hipStream_t stream) {
    (void)in_sizes; (void)n_in; (void)d_ws; (void)ws_size; (void)out_size;
    const float* knw = (const float*)d_in[0];  // [B,K,DK]
    const float* enc = (const float*)d_in[1];  // [B,T,DE]
    const float* W1  = (const float*)d_in[2];  // [DE,U]
    const float* b1  = (const float*)d_in[3];  // [U]
    const float* W2  = (const float*)d_in[4];  // [DK,U]
    const float* b2  = (const float*)d_in[5];  // [U]
    const float* V   = (const float*)d_in[6];  // [U,1]
    // d_in[7] = bV: constant over K, cancels in softmax -> unused.
    float* out = (float*)d_out;

    gemm_km<<<256, 256, 0, stream>>>(knw, W2, b2);
    attn_ctx<<<B_ * (T_ / TT_), 256, 0, stream>>>(knw, enc, W1, b1, V, out);
}

// Round 5
// 115.729 us; speedup vs baseline: 1.0483x; 1.0483x over previous
//
#include <hip/hip_runtime.h>

// Problem constants
#define B_  16
#define T_  256
#define K_  128
#define DK_ 256
#define U_  128
#define TT_ 4      // timesteps per attn block (grid = 16*64 = 1024 -> 4 blocks/CU)

#define SCALE_ 2.8853900817779268f  // 2*log2(e): exp(2x) = exp2(SCALE_*x)

// Km2 = exp2(SCALE_*(knw@W2+b2)) -- the only cross-kernel intermediate.
// (Cooperative single-kernel fusion fails under graph capture -> two
//  stream-ordered kernels. R4 lesson: do NOT hoist the km[16] prefetch to
//  the kernel top -- 64 VGPRs live across A1 forces scratch spills under
//  the 128-VGPR occupancy cap and cost +19 us.)
__device__ float g_Km2[B_ * K_ * U_];

// ---------------------------------------------------------------------------
// Km-only GEMM: 256 blocks x 256 threads (R3's 128 blocks used half the GPU
// on the serial critical path before attn_ctx). Block = 8 rows; W2 read
// ~once per block (33 MB L2 total, ~1 us), d-split across threads + LDS
// partial reduce. ~1024 fma/thread.
// ---------------------------------------------------------------------------
__global__ __launch_bounds__(256) void gemm_km(const float* __restrict__ knw,
                                               const float* __restrict__ W2,
                                               const float* __restrict__ b2) {
    __shared__ float Xs[8][256];        // 8 KB staged rows
    __shared__ float part[4][8][128];   // 16 KB dq-partials

    const int tid  = threadIdx.x;
    const int row0 = blockIdx.x * 8;    // flat row: b = row>>7, k = row&127

    // Stage 8 rows x 256 floats = 512 float4, 2 per thread, coalesced.
#pragma unroll
    for (int j = 0; j < 2; j++) {
        const int i  = tid + j * 256;
        const int rr = i >> 6, cc = i & 63;
        *(float4*)&Xs[rr][cc * 4] =
            *(const float4*)&knw[(row0 + rr) * 256 + cc * 4];
    }
    __syncthreads();

    // thread = (u4=4*(tid&31), dq=(tid>>5)&3, rh=tid>>7): 4 rows x 4 u x 64 d
    {
        const int uc = tid & 31;
        const int dq = (tid >> 5) & 3;
        const int rh = tid >> 7;
        float4 acc[4];
#pragma unroll
        for (int r = 0; r < 4; r++) acc[r] = make_float4(0.f, 0.f, 0.f, 0.f);
#pragma unroll 8
        for (int j = 0; j < 64; j++) {
            const int d = dq * 64 + j;
            const float4 w = *(const float4*)&W2[d * U_ + uc * 4];
#pragma unroll
            for (int r = 0; r < 4; r++) {
                const float x = Xs[rh * 4 + r][d];   // LDS broadcast
                acc[r].x = fmaf(x, w.x, acc[r].x);
                acc[r].y = fmaf(x, w.y, acc[r].y);
                acc[r].z = fmaf(x, w.z, acc[r].z);
                acc[r].w = fmaf(x, w.w, acc[r].w);
            }
        }
#pragma unroll
        for (int r = 0; r < 4; r++)
            *(float4*)&part[dq][rh * 4 + r][uc * 4] = acc[r];
    }
    __syncthreads();

    // Reduce 4 dq-partials: 1024 outputs / 256 threads = 4 each.
#pragma unroll
    for (int i = 0; i < 4; i++) {
        const int idx = tid + i * 256;
        const int r = idx >> 7, u = idx & 127;
        float s = b2[u];
#pragma unroll
        for (int dq = 0; dq < 4; dq++) s += part[dq][r][u];
        g_Km2[(row0 + r) * U_ + u] = __builtin_amdgcn_exp2f(SCALE_ * s);
    }
}

// ---------------------------------------------------------------------------
// Fused E-gemm -> scores -> softmax -> context. One block per (b, 4 t's).
// R3-proven structure: km loads issued AFTER the A1 barrier (short live
// range, latency covered by the A2 reduce; hoisting earlier spills -- R4).
// ---------------------------------------------------------------------------
__global__ __launch_bounds__(256, 4) void attn_ctx(const float* __restrict__ knw,
                                                   const float* __restrict__ enc,
                                                   const float* __restrict__ W1,
                                                   const float* __restrict__ b1,
                                                   const float* __restrict__ V,
                                                   float* __restrict__ out) {
    __shared__ float sm[4][TT_][256];   // 16 KB: E-partials / pA / ctx parts
    __shared__ float encs[TT_][256];    // 4 KB staged enc rows
    __shared__ float E2s[TT_][U_];      // 2 KB exp2 of own E rows
    __shared__ float attn[TT_][K_];     // 2 KB
    __shared__ float V2s[U_];           // 0.5 KB  2*V
    float* const smf = &sm[0][0][0];    // 4096 floats, multi-use

    const int tid  = threadIdx.x;
    const int blk  = blockIdx.x;
    const int b    = blk >> 6;          // 64 t-tiles per batch
    const int t0   = (blk & 63) * TT_;
    const int lane = tid & 63;
    const int wave = tid >> 6;

    // ---- A0: stage enc (4 rows x 256) + V ----
    {
        const int rr = tid >> 6, cc = tid & 63;
        *(float4*)&encs[rr][cc * 4] =
            *(const float4*)&enc[(b * T_ + t0 + rr) * 256 + cc * 4];
        if (tid < 128) V2s[tid] = 2.0f * V[tid];
    }
    __syncthreads();

    // ---- A1: E partial dots. thread = (u4=4*(tid&31), dq=tid>>5). ----
    // W1 read once per block, coalesced float4.
    {
        const int uc = tid & 31;
        const int dq = tid >> 5;        // d in [dq*32, dq*32+32)
        float4 a0 = {0,0,0,0}, a1 = {0,0,0,0}, a2 = {0,0,0,0}, a3 = {0,0,0,0};
#pragma unroll 8
        for (int j = 0; j < 32; j++) {
            const int d = dq * 32 + j;
            const float4 w = *(const float4*)&W1[d * U_ + uc * 4];
            const float e0 = encs[0][d], e1 = encs[1][d];
            const float e2 = encs[2][d], e3 = encs[3][d];
            a0.x = fmaf(e0, w.x, a0.x); a0.y = fmaf(e0, w.y, a0.y);
            a0.z = fmaf(e0, w.z, a0.z); a0.w = fmaf(e0, w.w, a0.w);
            a1.x = fmaf(e1, w.x, a1.x); a1.y = fmaf(e1, w.y, a1.y);
            a1.z = fmaf(e1, w.z, a1.z); a1.w = fmaf(e1, w.w, a1.w);
            a2.x = fmaf(e2, w.x, a2.x); a2.y = fmaf(e2, w.y, a2.y);
            a2.z = fmaf(e2, w.z, a2.z); a2.w = fmaf(e2, w.w, a2.w);
            a3.x = fmaf(e3, w.x, a3.x); a3.y = fmaf(e3, w.y, a3.y);
            a3.z = fmaf(e3, w.z, a3.z); a3.w = fmaf(e3, w.w, a3.w);
        }
        *(float4*)&smf[(dq * 4 + 0) * 128 + uc * 4] = a0;
        *(float4*)&smf[(dq * 4 + 1) * 128 + uc * 4] = a1;
        *(float4*)&smf[(dq * 4 + 2) * 128 + uc * 4] = a2;
        *(float4*)&smf[(dq * 4 + 3) * 128 + uc * 4] = a3;
    }
    __syncthreads();

    // km loads issued here (independent of LDS) -> overlap the A2 reduce.
    const int k_idx = tid & 127;
    const int half  = tid >> 7;
    float4 km[16];
    {
        const float* kp = &g_Km2[(b * K_ + k_idx) * U_ + half * 64];
#pragma unroll
        for (int c = 0; c < 16; c++) km[c] = *(const float4*)&kp[c * 4];
    }

    // ---- A2: reduce 8 dq-partials + bias + exp2 -> E2s ----
    {
        const int ti = tid >> 6, uu = tid & 63;
#pragma unroll
        for (int h = 0; h < 128; h += 64) {
            float s = b1[uu + h];
#pragma unroll
            for (int dq = 0; dq < 8; dq++)
                s += smf[(dq * 4 + ti) * 128 + uu + h];
            E2s[ti][uu + h] = __builtin_amdgcn_exp2f(SCALE_ * s);
        }
    }
    __syncthreads();

    float* const pA = smf;              // [TT_][256] score partials

    // ---- Phase 1: na[t] = sum_{u in half} 2V[u] * rcp(1 + ee*ek) ----
    // E2s/V2s reads are wave-uniform -> LDS broadcast. inf/0 products
    // saturate to the exact sigmoid limits (rcp(inf)=0, r=1).
    {
        float na[TT_] = {0.f, 0.f, 0.f, 0.f};
#pragma unroll
        for (int c = 0; c < 16; c++) {
            const float4 v4 = *(const float4*)&V2s[half * 64 + c * 4];
#pragma unroll
            for (int t = 0; t < TT_; t++) {
                const float4 e4 = *(const float4*)&E2s[t][half * 64 + c * 4];
                float r;
                r = __builtin_amdgcn_rcpf(fmaf(e4.x, km[c].x, 1.0f));
                na[t] = fmaf(v4.x, r, na[t]);
                r = __builtin_amdgcn_rcpf(fmaf(e4.y, km[c].y, 1.0f));
                na[t] = fmaf(v4.y, r, na[t]);
                r = __builtin_amdgcn_rcpf(fmaf(e4.z, km[c].z, 1.0f));
                na[t] = fmaf(v4.z, r, na[t]);
                r = __builtin_amdgcn_rcpf(fmaf(e4.w, km[c].w, 1.0f));
                na[t] = fmaf(v4.w, r, na[t]);
            }
        }
#pragma unroll
        for (int t = 0; t < TT_; t++) pA[t * 256 + tid] = na[t];
    }
    __syncthreads();

    // ---- Softmax over K=128: wave w owns timestep w ----
    {
        const int t = wave;
        const float* p = &pA[t * 256];
        float s0 = -(p[lane] + p[128 + lane]);
        float s1 = -(p[64 + lane] + p[192 + lane]);
        float m = fmaxf(s0, s1);
#pragma unroll
        for (int off = 32; off >= 1; off >>= 1)
            m = fmaxf(m, __shfl_xor(m, off));
        const float e0 = __builtin_amdgcn_exp2f(1.4426950408889634f * (s0 - m));
        const float e1 = __builtin_amdgcn_exp2f(1.4426950408889634f * (s1 - m));
        float ss = e0 + e1;
#pragma unroll
        for (int off = 32; off >= 1; off >>= 1)
            ss += __shfl_xor(ss, off);
        const float rinv = __builtin_amdgcn_rcpf(ss);
        attn[t][lane]      = e0 * rinv;
        attn[t][64 + lane] = e1 * rinv;
    }
    __syncthreads();

    // ---- Phase 2: context[ti][d] = sum_k attn[ti][k]*knw[b][k][d] ----
    // Wave kg covers k in [32kg, 32kg+32); lane covers d4 = 4*lane.
    {
        const int kg = wave, dq = lane;
        float4 acc[TT_];
#pragma unroll
        for (int ti = 0; ti < TT_; ti++) acc[ti] = make_float4(0.f, 0.f, 0.f, 0.f);

        const float* kp = &knw[(b * K_ + kg * 32) * DK_ + dq * 4];
#pragma unroll 4
        for (int ki = 0; ki < 32; ki++) {
            const float4 kn = *(const float4*)&kp[ki * DK_];
#pragma unroll
            for (int ti = 0; ti < TT_; ti++) {
                const float a = attn[ti][kg * 32 + ki];   // LDS broadcast
                acc[ti].x = fmaf(a, kn.x, acc[ti].x);
                acc[ti].y = fmaf(a, kn.y, acc[ti].y);
                acc[ti].z = fmaf(a, kn.z, acc[ti].z);
                acc[ti].w = fmaf(a, kn.w, acc[ti].w);
            }
        }
#pragma unroll
        for (int ti = 0; ti < TT_; ti++)
            *(float4*)&smf[(kg * TT_ + ti) * 256 + dq * 4] = acc[ti];
    }
    __syncthreads();

    // Cross-wave K reduction + coalesced float4 store (4 rows x 256)
    {
        const int ti = tid >> 6, dd = tid & 63;
        const float4 s0 = *(const float4*)&smf[(0 * TT_ + ti) * 256 + dd * 4];
        const float4 s1 = *(const float4*)&smf[(1 * TT_ + ti) * 256 + dd * 4];
        const float4 s2 = *(const float4*)&smf[(2 * TT_ + ti) * 256 + dd * 4];
        const float4 s3 = *(const float4*)&smf[(3 * TT_ + ti) * 256 + dd * 4];
        float4 o;
        o.x = s0.x + s1.x + s2.x + s3.x;
        o.y = s0.y + s1.y + s2.y + s3.y;
        o.z = s0.z + s1.z + s2.z + s3.z;
        o.w = s0.w + s1.w + s2.w + s3.w;
        *(float4*)&out[(b * T_ + t0 + ti) * DK_ + dd * 4] = o;
    }
}

// ---------------------------------------------------------------------------
extern "C" void kernel_launch(void* const* d_in, const int* in_sizes, int n_in,
                              void* d_out, int out_size, void* d_ws,
                              size_t ws_size, hipStream_t stream) {
    (void)in_sizes; (void)n_in; (void)d_ws; (void)ws_size; (void)out_size;
    const float* knw = (const float*)d_in[0];  // [B,K,DK]
    const float* enc = (const float*)d_in[1];  // [B,T,DE]
    const float* W1  = (const float*)d_in[2];  // [DE,U]
    const float* b1  = (const float*)d_in[3];  // [U]
    const float* W2  = (const float*)d_in[4];  // [DK,U]
    const float* b2  = (const float*)d_in[5];  // [U]
    const float* V   = (const float*)d_in[6];  // [U,1]
    // d_in[7] = bV: constant over K, cancels in softmax -> unused.
    float* out = (float*)d_out;

    gemm_km<<<256, 256, 0, stream>>>(knw, W2, b2);
    attn_ctx<<<B_ * (T_ / TT_), 256, 0, stream>>>(knw, enc, W1, b1, V, out);
}

// Round 6
// 102.103 us; speedup vs baseline: 1.1881x; 1.1335x over previous
//
#include <hip/hip_runtime.h>

// Problem constants
#define B_  16
#define T_  256
#define K_  128
#define DK_ 256
#define U_  128
#define TT_ 4      // timesteps per attn block (grid = 16*64 = 1024 -> 4 blocks/CU)

#define SCALE_ 2.8853900817779268f  // 2*log2(e): exp(2x) = exp2(SCALE_*x)

// Km2 = exp2(SCALE_*(knw@W2+b2)) -- the only cross-kernel intermediate.
// (Cooperative single-kernel fusion fails under graph capture -> two
//  stream-ordered kernels. R4 lesson: do NOT hoist the km[16] prefetch to
//  the kernel top -- long 64-VGPR live range spills. R5/R6 lesson: bench
//  run-to-run variance is ~+/-10 us -- this file is the byte-exact R3
//  config (102.3 us), re-submitted as an A/A reproducibility probe.)
__device__ float g_Km2[B_ * K_ * U_];

// ---------------------------------------------------------------------------
// Km-only GEMM: 128 blocks x 256 threads; block = 16 rows of the flattened
// [B*K]=2048 knowledge rows. W2 is read ~once per block (d-split across
// threads + LDS partial reduce): ~17 MB L2 traffic total. ALU-bound, ~2 us.
// (R5's 256x8 widening measured +13 us vs this -- mechanism unknown, possibly
//  noise; this probe decides.)
// ---------------------------------------------------------------------------
__global__ __launch_bounds__(256) void gemm_km(const float* __restrict__ knw,
                                               const float* __restrict__ W2,
                                               const float* __restrict__ b2) {
    __shared__ float Xs[16][256];       // 16 KB staged rows
    __shared__ float part[4][16][128];  // 32 KB dq-partials

    const int tid  = threadIdx.x;
    const int row0 = blockIdx.x * 16;   // flat row: b = row>>7, k = row&127

    // Stage 16 rows x 256 floats, coalesced float4.
#pragma unroll
    for (int j = 0; j < 4; j++) {
        const int i  = tid + j * 256;
        const int rr = i >> 6, cc = i & 63;
        *(float4*)&Xs[rr][cc * 4] =
            *(const float4*)&knw[(row0 + rr) * 256 + cc * 4];
    }
    __syncthreads();

    // thread = (u4=4*(tid&31), dq=(tid>>5)&3, rh=tid>>7): 8 rows x 4 u x 64 d
    {
        const int uc = tid & 31;
        const int dq = (tid >> 5) & 3;
        const int rh = tid >> 7;
        float4 acc[8];
#pragma unroll
        for (int r = 0; r < 8; r++) acc[r] = make_float4(0.f, 0.f, 0.f, 0.f);
#pragma unroll 8
        for (int j = 0; j < 64; j++) {
            const int d = dq * 64 + j;
            const float4 w = *(const float4*)&W2[d * U_ + uc * 4];
#pragma unroll
            for (int r = 0; r < 8; r++) {
                const float x = Xs[rh * 8 + r][d];   // LDS broadcast
                acc[r].x = fmaf(x, w.x, acc[r].x);
                acc[r].y = fmaf(x, w.y, acc[r].y);
                acc[r].z = fmaf(x, w.z, acc[r].z);
                acc[r].w = fmaf(x, w.w, acc[r].w);
            }
        }
#pragma unroll
        for (int r = 0; r < 8; r++)
            *(float4*)&part[dq][rh * 8 + r][uc * 4] = acc[r];
    }
    __syncthreads();

    // Reduce 4 dq-partials: 2048 outputs / 256 threads = 8 each.
#pragma unroll
    for (int i = 0; i < 8; i++) {
        const int idx = tid + i * 256;
        const int r = idx >> 7, u = idx & 127;
        float s = b2[u];
#pragma unroll
        for (int dq = 0; dq < 4; dq++) s += part[dq][r][u];
        g_Km2[(row0 + r) * U_ + u] = __builtin_amdgcn_exp2f(SCALE_ * s);
    }
}

// ---------------------------------------------------------------------------
// Fused E-gemm -> scores -> softmax -> context. One block per (b, 4 t's).
// Prologue computes this block's own 4 rows of exp2(SCALE*(enc@W1+b1)) into
// LDS (consumed only here -> no global round-trip; W1 read once per block).
// Then the R1-proven pipeline: phase1 r=rcp(fma(ee,ek,1)), softmax over K,
// context. km loads issued AFTER the A1 barrier (short live range).
// ---------------------------------------------------------------------------
__global__ __launch_bounds__(256, 4) void attn_ctx(const float* __restrict__ knw,
                                                   const float* __restrict__ enc,
                                                   const float* __restrict__ W1,
                                                   const float* __restrict__ b1,
                                                   const float* __restrict__ V,
                                                   float* __restrict__ out) {
    __shared__ float sm[4][TT_][256];   // 16 KB: E-partials / pA / ctx parts
    __shared__ float encs[TT_][256];    // 4 KB staged enc rows
    __shared__ float E2s[TT_][U_];      // 2 KB exp2 of own E rows
    __shared__ float attn[TT_][K_];     // 2 KB
    __shared__ float V2s[U_];           // 0.5 KB  2*V
    float* const smf = &sm[0][0][0];    // 4096 floats, multi-use

    const int tid  = threadIdx.x;
    const int blk  = blockIdx.x;
    const int b    = blk >> 6;          // 64 t-tiles per batch
    const int t0   = (blk & 63) * TT_;
    const int lane = tid & 63;
    const int wave = tid >> 6;

    // ---- A0: stage enc (4 rows x 256) + V ----
    {
        const int rr = tid >> 6, cc = tid & 63;
        *(float4*)&encs[rr][cc * 4] =
            *(const float4*)&enc[(b * T_ + t0 + rr) * 256 + cc * 4];
        if (tid < 128) V2s[tid] = 2.0f * V[tid];
    }
    __syncthreads();

    // ---- A1: E partial dots. thread = (u4=4*(tid&31), dq=tid>>5). ----
    // W1 read once per block, coalesced float4.
    {
        const int uc = tid & 31;
        const int dq = tid >> 5;        // d in [dq*32, dq*32+32)
        float4 a0 = {0,0,0,0}, a1 = {0,0,0,0}, a2 = {0,0,0,0}, a3 = {0,0,0,0};
#pragma unroll 8
        for (int j = 0; j < 32; j++) {
            const int d = dq * 32 + j;
            const float4 w = *(const float4*)&W1[d * U_ + uc * 4];
            const float e0 = encs[0][d], e1 = encs[1][d];
            const float e2 = encs[2][d], e3 = encs[3][d];
            a0.x = fmaf(e0, w.x, a0.x); a0.y = fmaf(e0, w.y, a0.y);
            a0.z = fmaf(e0, w.z, a0.z); a0.w = fmaf(e0, w.w, a0.w);
            a1.x = fmaf(e1, w.x, a1.x); a1.y = fmaf(e1, w.y, a1.y);
            a1.z = fmaf(e1, w.z, a1.z); a1.w = fmaf(e1, w.w, a1.w);
            a2.x = fmaf(e2, w.x, a2.x); a2.y = fmaf(e2, w.y, a2.y);
            a2.z = fmaf(e2, w.z, a2.z); a2.w = fmaf(e2, w.w, a2.w);
            a3.x = fmaf(e3, w.x, a3.x); a3.y = fmaf(e3, w.y, a3.y);
            a3.z = fmaf(e3, w.z, a3.z); a3.w = fmaf(e3, w.w, a3.w);
        }
        *(float4*)&smf[(dq * 4 + 0) * 128 + uc * 4] = a0;
        *(float4*)&smf[(dq * 4 + 1) * 128 + uc * 4] = a1;
        *(float4*)&smf[(dq * 4 + 2) * 128 + uc * 4] = a2;
        *(float4*)&smf[(dq * 4 + 3) * 128 + uc * 4] = a3;
    }
    __syncthreads();

    // km loads issued here (independent of LDS) -> overlap the A2 reduce.
    const int k_idx = tid & 127;
    const int half  = tid >> 7;
    float4 km[16];
    {
        const float* kp = &g_Km2[(b * K_ + k_idx) * U_ + half * 64];
#pragma unroll
        for (int c = 0; c < 16; c++) km[c] = *(const float4*)&kp[c * 4];
    }

    // ---- A2: reduce 8 dq-partials + bias + exp2 -> E2s ----
    {
        const int ti = tid >> 6, uu = tid & 63;
#pragma unroll
        for (int h = 0; h < 128; h += 64) {
            float s = b1[uu + h];
#pragma unroll
            for (int dq = 0; dq < 8; dq++)
                s += smf[(dq * 4 + ti) * 128 + uu + h];
            E2s[ti][uu + h] = __builtin_amdgcn_exp2f(SCALE_ * s);
        }
    }
    __syncthreads();

    float* const pA = smf;              // [TT_][256] score partials

    // ---- Phase 1: na[t] = sum_{u in half} 2V[u] * rcp(1 + ee*ek) ----
    // E2s/V2s reads are wave-uniform -> LDS broadcast. inf/0 products
    // saturate to the exact sigmoid limits (rcp(inf)=0, r=1).
    {
        float na[TT_] = {0.f, 0.f, 0.f, 0.f};
#pragma unroll
        for (int c = 0; c < 16; c++) {
            const float4 v4 = *(const float4*)&V2s[half * 64 + c * 4];
#pragma unroll
            for (int t = 0; t < TT_; t++) {
                const float4 e4 = *(const float4*)&E2s[t][half * 64 + c * 4];
                float r;
                r = __builtin_amdgcn_rcpf(fmaf(e4.x, km[c].x, 1.0f));
                na[t] = fmaf(v4.x, r, na[t]);
                r = __builtin_amdgcn_rcpf(fmaf(e4.y, km[c].y, 1.0f));
                na[t] = fmaf(v4.y, r, na[t]);
                r = __builtin_amdgcn_rcpf(fmaf(e4.z, km[c].z, 1.0f));
                na[t] = fmaf(v4.z, r, na[t]);
                r = __builtin_amdgcn_rcpf(fmaf(e4.w, km[c].w, 1.0f));
                na[t] = fmaf(v4.w, r, na[t]);
            }
        }
#pragma unroll
        for (int t = 0; t < TT_; t++) pA[t * 256 + tid] = na[t];
    }
    __syncthreads();

    // ---- Softmax over K=128: wave w owns timestep w ----
    {
        const int t = wave;
        const float* p = &pA[t * 256];
        float s0 = -(p[lane] + p[128 + lane]);
        float s1 = -(p[64 + lane] + p[192 + lane]);
        float m = fmaxf(s0, s1);
#pragma unroll
        for (int off = 32; off >= 1; off >>= 1)
            m = fmaxf(m, __shfl_xor(m, off));
        const float e0 = __builtin_amdgcn_exp2f(1.4426950408889634f * (s0 - m));
        const float e1 = __builtin_amdgcn_exp2f(1.4426950408889634f * (s1 - m));
        float ss = e0 + e1;
#pragma unroll
        for (int off = 32; off >= 1; off >>= 1)
            ss += __shfl_xor(ss, off);
        const float rinv = __builtin_amdgcn_rcpf(ss);
        attn[t][lane]      = e0 * rinv;
        attn[t][64 + lane] = e1 * rinv;
    }
    __syncthreads();

    // ---- Phase 2: context[ti][d] = sum_k attn[ti][k]*knw[b][k][d] ----
    // Wave kg covers k in [32kg, 32kg+32); lane covers d4 = 4*lane.
    {
        const int kg = wave, dq = lane;
        float4 acc[TT_];
#pragma unroll
        for (int ti = 0; ti < TT_; ti++) acc[ti] = make_float4(0.f, 0.f, 0.f, 0.f);

        const float* kp = &knw[(b * K_ + kg * 32) * DK_ + dq * 4];
#pragma unroll 4
        for (int ki = 0; ki < 32; ki++) {
            const float4 kn = *(const float4*)&kp[ki * DK_];
#pragma unroll
            for (int ti = 0; ti < TT_; ti++) {
                const float a = attn[ti][kg * 32 + ki];   // LDS broadcast
                acc[ti].x = fmaf(a, kn.x, acc[ti].x);
                acc[ti].y = fmaf(a, kn.y, acc[ti].y);
                acc[ti].z = fmaf(a, kn.z, acc[ti].z);
                acc[ti].w = fmaf(a, kn.w, acc[ti].w);
            }
        }
#pragma unroll
        for (int ti = 0; ti < TT_; ti++)
            *(float4*)&smf[(kg * TT_ + ti) * 256 + dq * 4] = acc[ti];
    }
    __syncthreads();

    // Cross-wave K reduction + coalesced float4 store (4 rows x 256)
    {
        const int ti = tid >> 6, dd = tid & 63;
        const float4 s0 = *(const float4*)&smf[(0 * TT_ + ti) * 256 + dd * 4];
        const float4 s1 = *(const float4*)&smf[(1 * TT_ + ti) * 256 + dd * 4];
        const float4 s2 = *(const float4*)&smf[(2 * TT_ + ti) * 256 + dd * 4];
        const float4 s3 = *(const float4*)&smf[(3 * TT_ + ti) * 256 + dd * 4];
        float4 o;
        o.x = s0.x + s1.x + s2.x + s3.x;
        o.y = s0.y + s1.y + s2.y + s3.y;
        o.z = s0.z + s1.z + s2.z + s3.z;
        o.w = s0.w + s1.w + s2.w + s3.w;
        *(float4*)&out[(b * T_ + t0 + ti) * DK_ + dd * 4] = o;
    }
}

// ---------------------------------------------------------------------------
extern "C" void kernel_launch(void* const* d_in, const int* in_sizes, int n_in,
                              void* d_out, int out_size, void* d_ws,
                              size_t ws_size, hipStream_t stream) {
    (void)in_sizes; (void)n_in; (void)d_ws; (void)ws_size; (void)out_size;
    const float* knw = (const float*)d_in[0];  // [B,K,DK]
    const float* enc = (const float*)d_in[1];  // [B,T,DE]
    const float* W1  = (const float*)d_in[2];  // [DE,U]
    const float* b1  = (const float*)d_in[3];  // [U]
    const float* W2  = (const float*)d_in[4];  // [DK,U]
    const float* b2  = (const float*)d_in[5];  // [U]
    const float* V   = (const float*)d_in[6];  // [U,1]
    // d_in[7] = bV: constant over K, cancels in softmax -> unused.
    float* out = (float*)d_out;

    gemm_km<<<128, 256, 0, stream>>>(knw, W2, b2);
    attn_ctx<<<B_ * (T_ / TT_), 256, 0, stream>>>(knw, enc, W1, b1, V, out);
}

// Round 10
// 101.233 us; speedup vs baseline: 1.1984x; 1.0086x over previous
//
#include <hip/hip_runtime.h>

// Problem constants
#define B_  16
#define T_  256
#define K_  128
#define DK_ 256
#define U_  128
#define TT_ 4      // timesteps per attn block (grid = 16*64 = 1024 -> 4 blocks/CU)

#define SCALE_ 2.8853900817779268f  // 2*log2(e): exp(2x) = exp2(SCALE_*x)

// Session ledger:
//  R1: exp2-precompute (5->3 slots/term)        -5.1 us   REAL
//  R3: E-gemm fused into attn prologue          -2.1 us   REAL
//  R4: km prefetch hoist -> VGPR spill          +6 us     AVOID
//  R5: gemm_km 256x8 (vs 128x16)                +13 us    AVOID (mech unknown)
//  R6: A/A probe: bench reproducible to +/-0.2%  (102.1 us baseline)
//  R7: op_sel_hi scalar-broadcast               COMPILE FAIL (f32 VOP3P needs
//      ALL sources as VGPR pairs).
//  R8/R9: hand-written v_pk_fma_f32 asm         NUMERIC FAIL both with and
//      without explicit op_sel modifiers -- VOP3P f32 modifier semantics not
//      what docs suggested. LESSON: never hand-write VOP3P; let the compiler
//      select it from <2 x float> ops (correct encoding guaranteed).
//  R10: phase 1 via ext_vector v2f + __builtin_elementwise_fma (this file).
//      Compiler forms v_pk_fma_f32 -> -256 slots/thread; worst case it
//      scalarizes -> neutral vs R6. Numerics bit-identical either way.
__device__ float g_Km2[B_ * K_ * U_];

typedef float v2f __attribute__((ext_vector_type(2)));

// ---------------------------------------------------------------------------
// Km-only GEMM: 128 blocks x 256 threads; block = 16 rows. W2 read ~once per
// block (d-split + LDS partial reduce). UNTOUCHED: R5 measured +13 us for the
// 256x8 variant; do not re-tile without a mechanism.
// ---------------------------------------------------------------------------
__global__ __launch_bounds__(256) void gemm_km(const float* __restrict__ knw,
                                               const float* __restrict__ W2,
                                               const float* __restrict__ b2) {
    __shared__ float Xs[16][256];       // 16 KB staged rows
    __shared__ float part[4][16][128];  // 32 KB dq-partials

    const int tid  = threadIdx.x;
    const int row0 = blockIdx.x * 16;   // flat row: b = row>>7, k = row&127

    // Stage 16 rows x 256 floats, coalesced float4.
#pragma unroll
    for (int j = 0; j < 4; j++) {
        const int i  = tid + j * 256;
        const int rr = i >> 6, cc = i & 63;
        *(float4*)&Xs[rr][cc * 4] =
            *(const float4*)&knw[(row0 + rr) * 256 + cc * 4];
    }
    __syncthreads();

    // thread = (u4=4*(tid&31), dq=(tid>>5)&3, rh=tid>>7): 8 rows x 4 u x 64 d
    {
        const int uc = tid & 31;
        const int dq = (tid >> 5) & 3;
        const int rh = tid >> 7;
        float4 acc[8];
#pragma unroll
        for (int r = 0; r < 8; r++) acc[r] = make_float4(0.f, 0.f, 0.f, 0.f);
#pragma unroll 8
        for (int j = 0; j < 64; j++) {
            const int d = dq * 64 + j;
            const float4 w = *(const float4*)&W2[d * U_ + uc * 4];
#pragma unroll
            for (int r = 0; r < 8; r++) {
                const float x = Xs[rh * 8 + r][d];   // LDS broadcast
                acc[r].x = fmaf(x, w.x, acc[r].x);
                acc[r].y = fmaf(x, w.y, acc[r].y);
                acc[r].z = fmaf(x, w.z, acc[r].z);
                acc[r].w = fmaf(x, w.w, acc[r].w);
            }
        }
#pragma unroll
        for (int r = 0; r < 8; r++)
            *(float4*)&part[dq][rh * 8 + r][uc * 4] = acc[r];
    }
    __syncthreads();

    // Reduce 4 dq-partials: 2048 outputs / 256 threads = 8 each.
#pragma unroll
    for (int i = 0; i < 8; i++) {
        const int idx = tid + i * 256;
        const int r = idx >> 7, u = idx & 127;
        float s = b2[u];
#pragma unroll
        for (int dq = 0; dq < 4; dq++) s += part[dq][r][u];
        g_Km2[(row0 + r) * U_ + u] = __builtin_amdgcn_exp2f(SCALE_ * s);
    }
}

// ---------------------------------------------------------------------------
// Fused E-gemm -> scores -> softmax -> context. One block per (b, 4 t's).
// Phase 1 uses <2 x float> vector ops (compiler-selected packed fp32).
// A1/phase2 stay scalar fma (outer-product broadcast not packable, R7).
// ---------------------------------------------------------------------------
__global__ __launch_bounds__(256, 4) void attn_ctx(const float* __restrict__ knw,
                                                   const float* __restrict__ enc,
                                                   const float* __restrict__ W1,
                                                   const float* __restrict__ b1,
                                                   const float* __restrict__ V,
                                                   float* __restrict__ out) {
    __shared__ float sm[4][TT_][256];   // 16 KB: E-partials / pA / ctx parts
    __shared__ float encs[TT_][256];    // 4 KB staged enc rows
    __shared__ float E2s[TT_][U_];      // 2 KB exp2 of own E rows
    __shared__ float attn[TT_][K_];     // 2 KB
    __shared__ float V2s[U_];           // 0.5 KB  2*V
    float* const smf = &sm[0][0][0];    // 4096 floats, multi-use

    const int tid  = threadIdx.x;
    const int blk  = blockIdx.x;
    const int b    = blk >> 6;          // 64 t-tiles per batch
    const int t0   = (blk & 63) * TT_;
    const int lane = tid & 63;
    const int wave = tid >> 6;

    // ---- A0: stage enc (4 rows x 256) + V ----
    {
        const int rr = tid >> 6, cc = tid & 63;
        *(float4*)&encs[rr][cc * 4] =
            *(const float4*)&enc[(b * T_ + t0 + rr) * 256 + cc * 4];
        if (tid < 128) V2s[tid] = 2.0f * V[tid];
    }
    __syncthreads();

    // ---- A1: E partial dots. thread = (u4=4*(tid&31), dq=tid>>5). ----
    // W1 read once per block, coalesced float4. Scalar fma.
    {
        const int uc = tid & 31;
        const int dq = tid >> 5;        // d in [dq*32, dq*32+32)
        float4 a0 = {0,0,0,0}, a1 = {0,0,0,0}, a2 = {0,0,0,0}, a3 = {0,0,0,0};
#pragma unroll 8
        for (int j = 0; j < 32; j++) {
            const int d = dq * 32 + j;
            const float4 w = *(const float4*)&W1[d * U_ + uc * 4];
            const float e0 = encs[0][d], e1 = encs[1][d];
            const float e2 = encs[2][d], e3 = encs[3][d];
            a0.x = fmaf(e0, w.x, a0.x); a0.y = fmaf(e0, w.y, a0.y);
            a0.z = fmaf(e0, w.z, a0.z); a0.w = fmaf(e0, w.w, a0.w);
            a1.x = fmaf(e1, w.x, a1.x); a1.y = fmaf(e1, w.y, a1.y);
            a1.z = fmaf(e1, w.z, a1.z); a1.w = fmaf(e1, w.w, a1.w);
            a2.x = fmaf(e2, w.x, a2.x); a2.y = fmaf(e2, w.y, a2.y);
            a2.z = fmaf(e2, w.z, a2.z); a2.w = fmaf(e2, w.w, a2.w);
            a3.x = fmaf(e3, w.x, a3.x); a3.y = fmaf(e3, w.y, a3.y);
            a3.z = fmaf(e3, w.z, a3.z); a3.w = fmaf(e3, w.w, a3.w);
        }
        *(float4*)&smf[(dq * 4 + 0) * 128 + uc * 4] = a0;
        *(float4*)&smf[(dq * 4 + 1) * 128 + uc * 4] = a1;
        *(float4*)&smf[(dq * 4 + 2) * 128 + uc * 4] = a2;
        *(float4*)&smf[(dq * 4 + 3) * 128 + uc * 4] = a3;
    }
    __syncthreads();

    // km loads issued here (short live range -- R4 lesson: do not hoist).
    const int k_idx = tid & 127;
    const int half  = tid >> 7;
    v2f km2[32];
    {
        const float* kp = &g_Km2[(b * K_ + k_idx) * U_ + half * 64];
#pragma unroll
        for (int c = 0; c < 16; c++) {
            const float4 t4 = *(const float4*)&kp[c * 4];
            km2[2 * c]     = (v2f){t4.x, t4.y};
            km2[2 * c + 1] = (v2f){t4.z, t4.w};
        }
    }

    // ---- A2: reduce 8 dq-partials + bias + exp2 -> E2s ----
    {
        const int ti = tid >> 6, uu = tid & 63;
#pragma unroll
        for (int h = 0; h < 128; h += 64) {
            float s = b1[uu + h];
#pragma unroll
            for (int dq = 0; dq < 8; dq++)
                s += smf[(dq * 4 + ti) * 128 + uu + h];
            E2s[ti][uu + h] = __builtin_amdgcn_exp2f(SCALE_ * s);
        }
    }
    __syncthreads();

    float* const pA = smf;              // [TT_][256] score partials

    // ---- Phase 1 (vector v2f): na[t] = sum_u 2V[u] * rcp(1 + ee*ek) ----
    // __builtin_elementwise_fma on v2f -> compiler selects v_pk_fma_f32
    // (correct encoding; R8/R9 hand-asm lesson). Per-element IEEE fma ->
    // numerics identical to scalar. inf/0 saturate to exact sigmoid limits.
    {
        v2f na2[TT_];
#pragma unroll
        for (int t = 0; t < TT_; t++) na2[t] = (v2f){0.f, 0.f};
        const v2f ones = {1.0f, 1.0f};
#pragma unroll
        for (int c = 0; c < 16; c++) {
            const float4 v4 = *(const float4*)&V2s[half * 64 + c * 4];
            const v2f vxy = {v4.x, v4.y}, vzw = {v4.z, v4.w};
            const v2f kxy = km2[2 * c], kzw = km2[2 * c + 1];
#pragma unroll
            for (int t = 0; t < TT_; t++) {
                const float4 e4 = *(const float4*)&E2s[t][half * 64 + c * 4];
                const v2f exy = {e4.x, e4.y}, ezw = {e4.z, e4.w};
                const v2f q0 = __builtin_elementwise_fma(exy, kxy, ones);
                const v2f q1 = __builtin_elementwise_fma(ezw, kzw, ones);
                v2f r0, r1;
                r0.x = __builtin_amdgcn_rcpf(q0.x);
                r0.y = __builtin_amdgcn_rcpf(q0.y);
                r1.x = __builtin_amdgcn_rcpf(q1.x);
                r1.y = __builtin_amdgcn_rcpf(q1.y);
                na2[t] = __builtin_elementwise_fma(vxy, r0, na2[t]);
                na2[t] = __builtin_elementwise_fma(vzw, r1, na2[t]);
            }
        }
#pragma unroll
        for (int t = 0; t < TT_; t++)
            pA[t * 256 + tid] = na2[t].x + na2[t].y;
    }
    __syncthreads();

    // ---- Softmax over K=128: wave w owns timestep w ----
    {
        const int t = wave;
        const float* p = &pA[t * 256];
        float s0 = -(p[lane] + p[128 + lane]);
        float s1 = -(p[64 + lane] + p[192 + lane]);
        float m = fmaxf(s0, s1);
#pragma unroll
        for (int off = 32; off >= 1; off >>= 1)
            m = fmaxf(m, __shfl_xor(m, off));
        const float e0 = __builtin_amdgcn_exp2f(1.4426950408889634f * (s0 - m));
        const float e1 = __builtin_amdgcn_exp2f(1.4426950408889634f * (s1 - m));
        float ss = e0 + e1;
#pragma unroll
        for (int off = 32; off >= 1; off >>= 1)
            ss += __shfl_xor(ss, off);
        const float rinv = __builtin_amdgcn_rcpf(ss);
        attn[t][lane]      = e0 * rinv;
        attn[t][64 + lane] = e1 * rinv;
    }
    __syncthreads();

    // ---- Phase 2: context[ti][d] = sum_k attn[ti][k]*knw[b][k][d] ----
    // Scalar fma. Wave kg covers k in [32kg, 32kg+32); lane covers d4.
    {
        const int kg = wave, dq = lane;
        float4 acc[TT_];
#pragma unroll
        for (int ti = 0; ti < TT_; ti++) acc[ti] = make_float4(0.f, 0.f, 0.f, 0.f);

        const float* kp = &knw[(b * K_ + kg * 32) * DK_ + dq * 4];
#pragma unroll 4
        for (int ki = 0; ki < 32; ki++) {
            const float4 kn = *(const float4*)&kp[ki * DK_];
#pragma unroll
            for (int ti = 0; ti < TT_; ti++) {
                const float a = attn[ti][kg * 32 + ki];   // LDS broadcast
                acc[ti].x = fmaf(a, kn.x, acc[ti].x);
                acc[ti].y = fmaf(a, kn.y, acc[ti].y);
                acc[ti].z = fmaf(a, kn.z, acc[ti].z);
                acc[ti].w = fmaf(a, kn.w, acc[ti].w);
            }
        }
#pragma unroll
        for (int ti = 0; ti < TT_; ti++)
            *(float4*)&smf[(kg * TT_ + ti) * 256 + dq * 4] = acc[ti];
    }
    __syncthreads();

    // Cross-wave K reduction + coalesced float4 store (4 rows x 256)
    {
        const int ti = tid >> 6, dd = tid & 63;
        const float4 s0 = *(const float4*)&smf[(0 * TT_ + ti) * 256 + dd * 4];
        const float4 s1 = *(const float4*)&smf[(1 * TT_ + ti) * 256 + dd * 4];
        const float4 s2 = *(const float4*)&smf[(2 * TT_ + ti) * 256 + dd * 4];
        const float4 s3 = *(const float4*)&smf[(3 * TT_ + ti) * 256 + dd * 4];
        float4 o;
        o.x = s0.x + s1.x + s2.x + s3.x;
        o.y = s0.y + s1.y + s2.y + s3.y;
        o.z = s0.z + s1.z + s2.z + s3.z;
        o.w = s0.w + s1.w + s2.w + s3.w;
        *(float4*)&out[(b * T_ + t0 + ti) * DK_ + dd * 4] = o;
    }
}

// ---------------------------------------------------------------------------
extern "C" void kernel_launch(void* const* d_in, const int* in_sizes, int n_in,
                              void* d_out, int out_size, void* d_ws,
                              size_t ws_size, hipStream_t stream) {
    (void)in_sizes; (void)n_in; (void)d_ws; (void)ws_size; (void)out_size;
    const float* knw = (const float*)d_in[0];  // [B,K,DK]
    const float* enc = (const float*)d_in[1];  // [B,T,DE]
    const float* W1  = (const float*)d_in[2];  // [DE,U]
    const float* b1  = (const float*)d_in[3];  // [U]
    const float* W2  = (const float*)d_in[4];  // [DK,U]
    const float* b2  = (const float*)d_in[5];  // [U]
    const float* V   = (const float*)d_in[6];  // [U,1]
    // d_in[7] = bV: constant over K, cancels in softmax -> unused.
    float* out = (float*)d_out;

    gemm_km<<<128, 256, 0, stream>>>(knw, W2, b2);
    attn_ctx<<<B_ * (T_ / TT_), 256, 0, stream>>>(knw, enc, W1, b1, V, out);
}

// Round 11
// 101.131 us; speedup vs baseline: 1.1996x; 1.0010x over previous
//
#include <hip/hip_runtime.h>

// Problem constants
#define B_  16
#define T_  256
#define K_  128
#define DK_ 256
#define U_  128
#define TT_ 4      // timesteps per attn block (grid = 16*64 = 1024 -> 4 blocks/CU)

#define SCALE_ 2.8853900817779268f  // 2*log2(e): exp(2x) = exp2(SCALE_*x)

// Session ledger:
//  R1: exp2-precompute (5->3 slots/term)        -5.1 us   REAL
//  R3: E-gemm fused into attn prologue          -2.1 us   REAL
//  R4: km prefetch hoist -> VGPR spill          +6 us     AVOID
//  R5: gemm_km 256x8 (vs 128x16)                +13 us    AVOID (mech unknown)
//  R6: A/A probe: bench reproducible to +/-0.2%  (102.1 us baseline)
//  R7-R9: hand-written VOP3P f32 asm: BANNED (compile fail / wrong encoding).
//  R10: phase 1 via v2f + __builtin_elementwise_fma  -0.9 us  REAL -- and
//       -0.9 us for -256 slots == the issue-bound model EXACTLY
//       (256 x 2cyc x 4 waves/SIMD = 0.85 us). attn_ctx is SLOT-BOUND.
//  R11: pack the REDUCTION dim (even/odd v2f chains + final hadd) in A1 and
//       phase 2 -- no scalar broadcast needed (R7 constraint respected).
__device__ float g_Km2[B_ * K_ * U_];

typedef float v2f __attribute__((ext_vector_type(2)));

// ---------------------------------------------------------------------------
// Km-only GEMM: 128 blocks x 256 threads; block = 16 rows. W2 read ~once per
// block (d-split + LDS partial reduce). UNTOUCHED: R5 measured +13 us for the
// 256x8 variant; do not re-tile without a mechanism.
// ---------------------------------------------------------------------------
__global__ __launch_bounds__(256) void gemm_km(const float* __restrict__ knw,
                                               const float* __restrict__ W2,
                                               const float* __restrict__ b2) {
    __shared__ float Xs[16][256];       // 16 KB staged rows
    __shared__ float part[4][16][128];  // 32 KB dq-partials

    const int tid  = threadIdx.x;
    const int row0 = blockIdx.x * 16;   // flat row: b = row>>7, k = row&127

    // Stage 16 rows x 256 floats, coalesced float4.
#pragma unroll
    for (int j = 0; j < 4; j++) {
        const int i  = tid + j * 256;
        const int rr = i >> 6, cc = i & 63;
        *(float4*)&Xs[rr][cc * 4] =
            *(const float4*)&knw[(row0 + rr) * 256 + cc * 4];
    }
    __syncthreads();

    // thread = (u4=4*(tid&31), dq=(tid>>5)&3, rh=tid>>7): 8 rows x 4 u x 64 d
    {
        const int uc = tid & 31;
        const int dq = (tid >> 5) & 3;
        const int rh = tid >> 7;
        float4 acc[8];
#pragma unroll
        for (int r = 0; r < 8; r++) acc[r] = make_float4(0.f, 0.f, 0.f, 0.f);
#pragma unroll 8
        for (int j = 0; j < 64; j++) {
            const int d = dq * 64 + j;
            const float4 w = *(const float4*)&W2[d * U_ + uc * 4];
#pragma unroll
            for (int r = 0; r < 8; r++) {
                const float x = Xs[rh * 8 + r][d];   // LDS broadcast
                acc[r].x = fmaf(x, w.x, acc[r].x);
                acc[r].y = fmaf(x, w.y, acc[r].y);
                acc[r].z = fmaf(x, w.z, acc[r].z);
                acc[r].w = fmaf(x, w.w, acc[r].w);
            }
        }
#pragma unroll
        for (int r = 0; r < 8; r++)
            *(float4*)&part[dq][rh * 8 + r][uc * 4] = acc[r];
    }
    __syncthreads();

    // Reduce 4 dq-partials: 2048 outputs / 256 threads = 8 each.
#pragma unroll
    for (int i = 0; i < 8; i++) {
        const int idx = tid + i * 256;
        const int r = idx >> 7, u = idx & 127;
        float s = b2[u];
#pragma unroll
        for (int dq = 0; dq < 4; dq++) s += part[dq][r][u];
        g_Km2[(row0 + r) * U_ + u] = __builtin_amdgcn_exp2f(SCALE_ * s);
    }
}

// ---------------------------------------------------------------------------
// Fused E-gemm -> scores -> softmax -> context. One block per (b, 4 t's).
// A1 and phase 2 pack the reduction dim into even/odd v2f chains
// (horizontal add at the end); phase 1 packed as in R10.
// ---------------------------------------------------------------------------
__global__ __launch_bounds__(256, 4) void attn_ctx(const float* __restrict__ knw,
                                                   const float* __restrict__ enc,
                                                   const float* __restrict__ W1,
                                                   const float* __restrict__ b1,
                                                   const float* __restrict__ V,
                                                   float* __restrict__ out) {
    __shared__ float sm[4][TT_][256];   // 16 KB: E-partials / pA / ctx parts
    __shared__ float encs[TT_][256];    // 4 KB staged enc rows
    __shared__ float E2s[TT_][U_];      // 2 KB exp2 of own E rows
    __shared__ float attn[TT_][K_];     // 2 KB
    __shared__ float V2s[U_];           // 0.5 KB  2*V
    float* const smf = &sm[0][0][0];    // 4096 floats, multi-use

    const int tid  = threadIdx.x;
    const int blk  = blockIdx.x;
    const int b    = blk >> 6;          // 64 t-tiles per batch
    const int t0   = (blk & 63) * TT_;
    const int lane = tid & 63;
    const int wave = tid >> 6;

    // ---- A0: stage enc (4 rows x 256) + V ----
    {
        const int rr = tid >> 6, cc = tid & 63;
        *(float4*)&encs[rr][cc * 4] =
            *(const float4*)&enc[(b * T_ + t0 + rr) * 256 + cc * 4];
        if (tid < 128) V2s[tid] = 2.0f * V[tid];
    }
    __syncthreads();

    // ---- A1 (packed over d-pairs): E partial dots. thread = (u4, dq). ----
    // Even/odd d chains in v2f lanes; e-pairs are natural contiguous LDS
    // v2f reads; W packs transposed once per d-pair, shared across 4 t's.
    {
        const int uc = tid & 31;
        const int dq = tid >> 5;        // d in [dq*32, dq*32+32)
        v2f a0x={0,0}, a0y={0,0}, a0z={0,0}, a0w={0,0};
        v2f a1x={0,0}, a1y={0,0}, a1z={0,0}, a1w={0,0};
        v2f a2x={0,0}, a2y={0,0}, a2z={0,0}, a2w={0,0};
        v2f a3x={0,0}, a3y={0,0}, a3z={0,0}, a3w={0,0};
#pragma unroll 4
        for (int j = 0; j < 16; j++) {
            const int d = dq * 32 + 2 * j;
            const float4 we = *(const float4*)&W1[d * U_ + uc * 4];
            const float4 wo = *(const float4*)&W1[(d + 1) * U_ + uc * 4];
            const v2f wx = {we.x, wo.x}, wy = {we.y, wo.y};
            const v2f wz = {we.z, wo.z}, ww = {we.w, wo.w};
            const v2f e0 = *(const v2f*)&encs[0][d];
            const v2f e1 = *(const v2f*)&encs[1][d];
            const v2f e2 = *(const v2f*)&encs[2][d];
            const v2f e3 = *(const v2f*)&encs[3][d];
            a0x = __builtin_elementwise_fma(e0, wx, a0x);
            a0y = __builtin_elementwise_fma(e0, wy, a0y);
            a0z = __builtin_elementwise_fma(e0, wz, a0z);
            a0w = __builtin_elementwise_fma(e0, ww, a0w);
            a1x = __builtin_elementwise_fma(e1, wx, a1x);
            a1y = __builtin_elementwise_fma(e1, wy, a1y);
            a1z = __builtin_elementwise_fma(e1, wz, a1z);
            a1w = __builtin_elementwise_fma(e1, ww, a1w);
            a2x = __builtin_elementwise_fma(e2, wx, a2x);
            a2y = __builtin_elementwise_fma(e2, wy, a2y);
            a2z = __builtin_elementwise_fma(e2, wz, a2z);
            a2w = __builtin_elementwise_fma(e2, ww, a2w);
            a3x = __builtin_elementwise_fma(e3, wx, a3x);
            a3y = __builtin_elementwise_fma(e3, wy, a3y);
            a3z = __builtin_elementwise_fma(e3, wz, a3z);
            a3w = __builtin_elementwise_fma(e3, ww, a3w);
        }
        const float4 r0 = {a0x.x + a0x.y, a0y.x + a0y.y, a0z.x + a0z.y, a0w.x + a0w.y};
        const float4 r1 = {a1x.x + a1x.y, a1y.x + a1y.y, a1z.x + a1z.y, a1w.x + a1w.y};
        const float4 r2 = {a2x.x + a2x.y, a2y.x + a2y.y, a2z.x + a2z.y, a2w.x + a2w.y};
        const float4 r3 = {a3x.x + a3x.y, a3y.x + a3y.y, a3z.x + a3z.y, a3w.x + a3w.y};
        *(float4*)&smf[(dq * 4 + 0) * 128 + uc * 4] = r0;
        *(float4*)&smf[(dq * 4 + 1) * 128 + uc * 4] = r1;
        *(float4*)&smf[(dq * 4 + 2) * 128 + uc * 4] = r2;
        *(float4*)&smf[(dq * 4 + 3) * 128 + uc * 4] = r3;
    }
    __syncthreads();

    // km loads issued here (short live range -- R4 lesson: do not hoist).
    const int k_idx = tid & 127;
    const int half  = tid >> 7;
    v2f km2[32];
    {
        const float* kp = &g_Km2[(b * K_ + k_idx) * U_ + half * 64];
#pragma unroll
        for (int c = 0; c < 16; c++) {
            const float4 t4 = *(const float4*)&kp[c * 4];
            km2[2 * c]     = (v2f){t4.x, t4.y};
            km2[2 * c + 1] = (v2f){t4.z, t4.w};
        }
    }

    // ---- A2: reduce 8 dq-partials + bias + exp2 -> E2s ----
    {
        const int ti = tid >> 6, uu = tid & 63;
#pragma unroll
        for (int h = 0; h < 128; h += 64) {
            float s = b1[uu + h];
#pragma unroll
            for (int dq = 0; dq < 8; dq++)
                s += smf[(dq * 4 + ti) * 128 + uu + h];
            E2s[ti][uu + h] = __builtin_amdgcn_exp2f(SCALE_ * s);
        }
    }
    __syncthreads();

    float* const pA = smf;              // [TT_][256] score partials

    // ---- Phase 1 (v2f, as R10): na[t] = sum_u 2V[u] * rcp(1 + ee*ek) ----
    {
        v2f na2[TT_];
#pragma unroll
        for (int t = 0; t < TT_; t++) na2[t] = (v2f){0.f, 0.f};
        const v2f ones = {1.0f, 1.0f};
#pragma unroll
        for (int c = 0; c < 16; c++) {
            const float4 v4 = *(const float4*)&V2s[half * 64 + c * 4];
            const v2f vxy = {v4.x, v4.y}, vzw = {v4.z, v4.w};
            const v2f kxy = km2[2 * c], kzw = km2[2 * c + 1];
#pragma unroll
            for (int t = 0; t < TT_; t++) {
                const float4 e4 = *(const float4*)&E2s[t][half * 64 + c * 4];
                const v2f exy = {e4.x, e4.y}, ezw = {e4.z, e4.w};
                const v2f q0 = __builtin_elementwise_fma(exy, kxy, ones);
                const v2f q1 = __builtin_elementwise_fma(ezw, kzw, ones);
                v2f r0, r1;
                r0.x = __builtin_amdgcn_rcpf(q0.x);
                r0.y = __builtin_amdgcn_rcpf(q0.y);
                r1.x = __builtin_amdgcn_rcpf(q1.x);
                r1.y = __builtin_amdgcn_rcpf(q1.y);
                na2[t] = __builtin_elementwise_fma(vxy, r0, na2[t]);
                na2[t] = __builtin_elementwise_fma(vzw, r1, na2[t]);
            }
        }
#pragma unroll
        for (int t = 0; t < TT_; t++)
            pA[t * 256 + tid] = na2[t].x + na2[t].y;
    }
    __syncthreads();

    // ---- Softmax over K=128: wave w owns timestep w ----
    {
        const int t = wave;
        const float* p = &pA[t * 256];
        float s0 = -(p[lane] + p[128 + lane]);
        float s1 = -(p[64 + lane] + p[192 + lane]);
        float m = fmaxf(s0, s1);
#pragma unroll
        for (int off = 32; off >= 1; off >>= 1)
            m = fmaxf(m, __shfl_xor(m, off));
        const float e0 = __builtin_amdgcn_exp2f(1.4426950408889634f * (s0 - m));
        const float e1 = __builtin_amdgcn_exp2f(1.4426950408889634f * (s1 - m));
        float ss = e0 + e1;
#pragma unroll
        for (int off = 32; off >= 1; off >>= 1)
            ss += __shfl_xor(ss, off);
        const float rinv = __builtin_amdgcn_rcpf(ss);
        attn[t][lane]      = e0 * rinv;
        attn[t][64 + lane] = e1 * rinv;
    }
    __syncthreads();

    // ---- Phase 2 (packed over k-pairs): ctx[ti][d] = sum_k a*knw ----
    // Even/odd k chains in v2f lanes; a-pairs are natural contiguous LDS
    // v2f reads (ds_read_b64); kn packs transposed once per pair, shared
    // across the 4 ti's. Horizontal add folded into the partial store.
    {
        const int kg = wave, dq = lane;
        v2f acx[TT_], acy[TT_], acz[TT_], acw[TT_];
#pragma unroll
        for (int ti = 0; ti < TT_; ti++) {
            acx[ti] = (v2f){0.f, 0.f}; acy[ti] = (v2f){0.f, 0.f};
            acz[ti] = (v2f){0.f, 0.f}; acw[ti] = (v2f){0.f, 0.f};
        }
        const float* kp = &knw[(b * K_ + kg * 32) * DK_ + dq * 4];
#pragma unroll 4
        for (int ki = 0; ki < 32; ki += 2) {
            const float4 ke = *(const float4*)&kp[ki * DK_];
            const float4 ko = *(const float4*)&kp[(ki + 1) * DK_];
            const v2f kx = {ke.x, ko.x}, ky = {ke.y, ko.y};
            const v2f kz = {ke.z, ko.z}, kw = {ke.w, ko.w};
#pragma unroll
            for (int ti = 0; ti < TT_; ti++) {
                const v2f av = *(const v2f*)&attn[ti][kg * 32 + ki];
                acx[ti] = __builtin_elementwise_fma(av, kx, acx[ti]);
                acy[ti] = __builtin_elementwise_fma(av, ky, acy[ti]);
                acz[ti] = __builtin_elementwise_fma(av, kz, acz[ti]);
                acw[ti] = __builtin_elementwise_fma(av, kw, acw[ti]);
            }
        }
#pragma unroll
        for (int ti = 0; ti < TT_; ti++) {
            const float4 r = {acx[ti].x + acx[ti].y, acy[ti].x + acy[ti].y,
                              acz[ti].x + acz[ti].y, acw[ti].x + acw[ti].y};
            *(float4*)&smf[(kg * TT_ + ti) * 256 + dq * 4] = r;
        }
    }
    __syncthreads();

    // Cross-wave K reduction + coalesced float4 store (4 rows x 256)
    {
        const int ti = tid >> 6, dd = tid & 63;
        const float4 s0 = *(const float4*)&smf[(0 * TT_ + ti) * 256 + dd * 4];
        const float4 s1 = *(const float4*)&smf[(1 * TT_ + ti) * 256 + dd * 4];
        const float4 s2 = *(const float4*)&smf[(2 * TT_ + ti) * 256 + dd * 4];
        const float4 s3 = *(const float4*)&smf[(3 * TT_ + ti) * 256 + dd * 4];
        float4 o;
        o.x = s0.x + s1.x + s2.x + s3.x;
        o.y = s0.y + s1.y + s2.y + s3.y;
        o.z = s0.z + s1.z + s2.z + s3.z;
        o.w = s0.w + s1.w + s2.w + s3.w;
        *(float4*)&out[(b * T_ + t0 + ti) * DK_ + dd * 4] = o;
    }
}

// ---------------------------------------------------------------------------
extern "C" void kernel_launch(void* const* d_in, const int* in_sizes, int n_in,
                              void* d_out, int out_size, void* d_ws,
                              size_t ws_size, hipStream_t stream) {
    (void)in_sizes; (void)n_in; (void)d_ws; (void)ws_size; (void)out_size;
    const float* knw = (const float*)d_in[0];  // [B,K,DK]
    const float* enc = (const float*)d_in[1];  // [B,T,DE]
    const float* W1  = (const float*)d_in[2];  // [DE,U]
    const float* b1  = (const float*)d_in[3];  // [U]
    const float* W2  = (const float*)d_in[4];  // [DK,U]
    const float* b2  = (const float*)d_in[5];  // [U]
    const float* V   = (const float*)d_in[6];  // [U,1]
    // d_in[7] = bV: constant over K, cancels in softmax -> unused.
    float* out = (float*)d_out;

    gemm_km<<<128, 256, 0, stream>>>(knw, W2, b2);
    attn_ctx<<<B_ * (T_ / TT_), 256, 0, stream>>>(knw, enc, W1, b1, V, out);
}